// Round 31
// baseline (62.285 us; speedup 1.0000x reference)
//
#include <hip/hip_runtime.h>

// Problem constants
#define BDIM   16
#define PDIM   12
#define TDIM   4096
#define WINW   41
#define PADW   20
#define DDIM   492      // P*WIN
#define KCODES 1024

// R30 (MXFP4 B + fp8 A via mfma_scale_f32_16x16x128_f8f6f4, blgp=4): 61.8us
// graph, absmax 0. Pipe accounting: MFMA 15us, LDS 26us, VALU ~39K cyc (28%)
// -- address arithmetic dominates the VALU surplus. R31: unroll the tile
// sweep so all LDS reads become base+immediate-offset (16-bit DS offset field
// covers the 64 KiB quarter), and hoist the B operand so only its lower half
// (the half blgp=4 reads) is written per MFMA.
#define KCHUNK   4                   // K=128 chunks covering 512
#define TILEB    4096                // 4 kc x 64 lanes x 16 B fp4 per 16-code tile
#define NTILES   64

#define WAVES    16                  // 1024-thread blocks (4 waves/SIMD)
#define ROWS_WAVE 16
#define BMROWS   (WAVES * ROWS_WAVE) // 256 rows per block
#define MROWS    (BDIM * TDIM)       // 65536
#define NBLK     (MROWS / BMROWS)    // 256 = 1 block/CU, single round
#define NQ       4                   // codebook quarters (B restaged)
#define QTILES   16
#define QBYTES   (QTILES * TILEB)    // 64 KiB per B quarter
#define SBYTES   (NTILES * 1024)     // 64 KiB scale table (all tiles, resident)

#define SCALE1   0x7F7F7F7F          // e8m0 127 = 1.0 (A side)

typedef __attribute__((ext_vector_type(4))) float f32x4;
typedef __attribute__((ext_vector_type(4))) int   int4v;
typedef __attribute__((ext_vector_type(8))) int   int8v;

// two f32 pairs -> 4 e4m3 bytes (RNE, saturating) via v_cvt_pk_fp8_f32
__device__ __forceinline__ unsigned int pack4_fp8(float a, float b, float c, float d) {
    int v = 0;
    v = __builtin_amdgcn_cvt_pk_fp8_f32(a, b, v, false);  // bytes 0,1
    v = __builtin_amdgcn_cvt_pk_fp8_f32(c, d, v, true);   // bytes 2,3
    return (unsigned int)v;
}

// e2m1 encode of u (already divided by block scale): nearest of
// {0,.5,1,1.5,2,3,4,6}, sign in bit 3.
__device__ __forceinline__ unsigned enc_fp4(float u) {
    unsigned s = (u < 0.f) ? 8u : 0u;
    float a = fabsf(u);
    unsigned c;
    if      (a < 0.25f) c = 0;
    else if (a < 0.75f) c = 1;
    else if (a < 1.25f) c = 2;
    else if (a < 1.75f) c = 3;
    else if (a < 2.5f)  c = 4;
    else if (a < 3.5f)  c = 5;
    else if (a < 5.0f)  c = 6;
    else                c = 7;
    return s | c;
}

// Pre-format codebook into MXFP4 B-fragments + e8m0 scale table.
// IDENTICAL to R30 (verified absmax 0).
__global__ __launch_bounds__(256) void prep_bfp4_k(const float* __restrict__ cb,
                                                   unsigned int* __restrict__ bfp4,
                                                   unsigned int* __restrict__ bscale) {
    int e    = blockIdx.x * 256 + threadIdx.x;   // 0..16383
    int lane = e & 63;
    int kc   = (e >> 6) & (KCHUNK - 1);
    int nt   = e >> 8;
    int n    = nt * 16 + (lane & 15);
    int kbase = kc * 128 + (lane >> 4) * 32;
    float v[32];
    float mx = 0.f;
#pragma unroll
    for (int j = 0; j < 32; ++j) {
        int k = kbase + j;
        float f = (k < DDIM) ? cb[n * DDIM + k] : 0.f;
        v[j] = f;
        mx = fmaxf(mx, fabsf(f));
    }
    int eb; float inv;
    if (mx == 0.f) { eb = 127; inv = 1.f; }
    else {
        int ee = (int)ceilf(log2f(mx * (1.0f / 6.0f)));
        ee = min(127, max(-127, ee));
        eb = ee + 127;
        inv = exp2f((float)(-ee));
    }
    unsigned w[4];
#pragma unroll
    for (int wi = 0; wi < 4; ++wi) {
        unsigned acc = 0;
#pragma unroll
        for (int b = 0; b < 8; ++b)
            acc |= enc_fp4(v[wi * 8 + b] * inv) << (4 * b);
        w[wi] = acc;
    }
    int4v out; out[0] = (int)w[0]; out[1] = (int)w[1]; out[2] = (int)w[2]; out[3] = (int)w[3];
    *(int4v*)(bfp4 + (size_t)e * 4) = out;
    bscale[nt * 256 + lane * 4 + kc] = (unsigned)eb * 0x01010101u;
}

// Exact fp32 code norms.
__global__ __launch_bounds__(64) void prep_cnorm_k(const float* __restrict__ cb,
                                                   float* __restrict__ cnorm) {
    int n = blockIdx.x;
    int lane = threadIdx.x;
    float s = 0.f;
    for (int d = lane; d < DDIM; d += 64) { float c = cb[n * DDIM + d]; s += c * c; }
#pragma unroll
    for (int m = 1; m < 64; m <<= 1) s += __shfl_xor(s, m, 64);
    if (lane == 0) cnorm[n] = s;
}

// Exact sum of ||f||^2 over all rows via window multiplicity:
// mult(tt) = 41 - max(0,20-tt) - max(0,tt-4075).
__global__ __launch_bounds__(256) void xsq_k(const float* __restrict__ x,
                                             float* __restrict__ xsq_part) {
    float s = 0.f;
    for (int i = blockIdx.x * 256 + threadIdx.x; i < BDIM * PDIM * TDIM; i += 256 * 256) {
        int tt = i & (TDIM - 1);
        int mult = WINW - max(0, PADW - tt) - max(0, tt - (TDIM - 1 - PADW));
        float v = x[i];
        s += (float)mult * v * v;
    }
#pragma unroll
    for (int m = 1; m < 64; m <<= 1) s += __shfl_xor(s, m, 64);
    __shared__ float sm[4];
    if ((threadIdx.x & 63) == 0) sm[threadIdx.x >> 6] = s;
    __syncthreads();
    if (threadIdx.x == 0) xsq_part[blockIdx.x] = sm[0] + sm[1] + sm[2] + sm[3];
}

// Stage `rounds` x 16 KiB into LDS (1024 thr x 16 B per round, linear).
__device__ __forceinline__ void stage_lin(const unsigned char* __restrict__ g,
                                          unsigned char* smem, int rounds,
                                          int wave, int lane) {
    for (int i = 0; i < rounds; ++i) {
        int off = i * 16384 + wave * 1024;
        __builtin_amdgcn_global_load_lds(
            (const __attribute__((address_space(1))) unsigned int*)(g + off + lane * 16),
            (__attribute__((address_space(3))) unsigned int*)(smem + off),
            16, 0, 0);
    }
}

// windowed-x fetch: element d of row with time-index t
__device__ __forceinline__ float fetchx(const float* __restrict__ xb, int t, int d) {
    if (d >= DDIM) return 0.f;
    int p  = d / WINW;
    int w  = d - p * WINW;
    int tt = t + w - PADW;
    return (tt >= 0 && tt < TDIM) ? xb[p * TDIM + tt] : 0.f;
}

// Main sweep: 256 blocks (1/CU) x 16 waves x 16 rows, single round.
// Unrolled tile sweep -> all LDS reads are base+imm-offset; B operand upper
// half written once (blgp=4 only reads the lower half).
__global__ __launch_bounds__(1024)
void vq_main_k(const float* __restrict__ x,
               const unsigned char* __restrict__ bfp4,
               const unsigned char* __restrict__ bscale,
               const float* __restrict__ cnorm,
               float* __restrict__ bpart) {
    __shared__ __align__(16) unsigned char smemB[QBYTES];   // 64 KiB (B quarter)
    __shared__ __align__(16) unsigned char smemS[SBYTES];   // 64 KiB (all scales)
    __shared__ float sb_lds[KCODES];                        // 4 KiB
    __shared__ float gsum[4 * WAVES];

    const int lane = threadIdx.x & 63;
    const int wave = threadIdx.x >> 6;
    const int col  = lane & 15;     // B/D column within 16-code tile
    const int hi   = lane >> 4;
    const int rowbase = blockIdx.x * BMROWS + wave * ROWS_WAVE;

    // Stage scales (whole table) + B quarter 0; latency covered below.
    stage_lin(bscale, smemS, 4, wave, lane);
    stage_lin(bfp4, smemB, 4, wave, lane);

    // Full bias table: sb_lds[n] = -0.5*||c_n||^2
    for (int i = threadIdx.x; i < KCODES; i += 1024)
        sb_lds[i] = -0.5f * cnorm[i];

    // ---- fp8 A-build: row = rowbase + col, k = kc*128 + hi*32 + 4m + b ----
    int8v afr[KCHUNK];
    {
        int row = rowbase + col;
        int t = row & (TDIM - 1);
        const float* xb = x + (size_t)(row >> 12) * (PDIM * TDIM);
#pragma unroll
        for (int kc = 0; kc < KCHUNK; ++kc) {
#pragma unroll
            for (int m = 0; m < 8; ++m) {
                int d = kc * 128 + hi * 32 + m * 4;
                afr[kc][m] = (int)pack4_fp8(fetchx(xb, t, d + 0), fetchx(xb, t, d + 1),
                                            fetchx(xb, t, d + 2), fetchx(xb, t, d + 3));
            }
            __builtin_amdgcn_sched_barrier(0);   // bound prologue pressure
        }
    }

    float bs[4];
#pragma unroll
    for (int r = 0; r < 4; ++r) bs[r] = -3.0e38f;

    // Entry drain: scales + quarter 0 resident; sb_lds visible.
    __syncthreads();

    // B operand: upper half (unused under blgp=4) initialized once.
    int8v b;
#pragma unroll
    for (int i = 0; i < 8; ++i) b[i] = 0;

    const unsigned char* bbase = smemB + lane * 16;   // imm offsets cover 64 KiB
    const unsigned char* sbase = smemS + lane * 16;

    for (int q = 0; q < NQ; ++q) {
        // ---- Barrier-free sweep; fully unrolled -> imm-offset ds_reads ----
#pragma unroll
        for (int tl = 0; tl < QTILES; ++tl) {
            const int gt = q * QTILES + tl;
            int4v scw = *(const int4v*)(sbase + gt * 1024);
            f32x4 acc = {0.f, 0.f, 0.f, 0.f};
#pragma unroll
            for (int kc = 0; kc < KCHUNK; ++kc) {
                *(int4v*)&b = *(const int4v*)(bbase + tl * TILEB + kc * 1024);
                acc = __builtin_amdgcn_mfma_scale_f32_16x16x128_f8f6f4(
                          afr[kc], b, acc, 0, 4, 0, SCALE1, 0, scw[kc]);
            }
            const float sb = sb_lds[gt * 16 + col];
#pragma unroll
            for (int r = 0; r < 4; ++r)          // D: col=lane&15, row=hi*4+r
                bs[r] = fmaxf(bs[r], acc[r] + sb);
        }
        // ---- Restage next B quarter (2 barriers per transition) ----
        if (q + 1 < NQ) {
            __syncthreads();   // all waves done reading smemB
            stage_lin(bfp4 + (size_t)(q + 1) * QBYTES, smemB, 4, wave, lane);
            __syncthreads();   // drains vmcnt(0): next quarter resident
        }
    }

    // ---- Per-row max across the 16 col-lanes (masks<16 preserve hi) ----
#pragma unroll
    for (int m = 1; m < 16; m <<= 1)
#pragma unroll
        for (int r = 0; r < 4; ++r)
            bs[r] = fmaxf(bs[r], __shfl_xor(bs[r], m, 64));

    // Lane col==0 of each 16-lane group owns rows {hi*4 + r} of the slab.
    if (col == 0) {
        float s = 0.f;
#pragma unroll
        for (int r = 0; r < 4; ++r) s += bs[r];
        gsum[wave * 4 + hi] = s;
    }
    __syncthreads();
    if (threadIdx.x == 0) {
        float tot = 0.f;
#pragma unroll
        for (int i = 0; i < 4 * WAVES; ++i) tot += gsum[i];
        bpart[blockIdx.x] = tot;
    }
}

// loss = 0.25 * (Sxx - 2*sum_blocks bpart) / (65536*492)
__global__ __launch_bounds__(256) void finalize_k(const float* __restrict__ bpart,
                                                  const float* __restrict__ xsq_part,
                                                  float* __restrict__ out) {
    __shared__ double sm[256];
    int tid = threadIdx.x;
    sm[tid] = (double)bpart[tid];
    __syncthreads();
    for (int st = 128; st > 0; st >>= 1) {
        if (tid < st) sm[tid] += sm[tid + st];
        __syncthreads();
    }
    double S1 = sm[0];
    __syncthreads();
    sm[tid] = (double)xsq_part[tid];
    __syncthreads();
    for (int st = 128; st > 0; st >>= 1) {
        if (tid < st) sm[tid] += sm[tid + st];
        __syncthreads();
    }
    if (tid == 0)
        out[0] = (float)(0.25 * (sm[0] - 2.0 * S1) / ((double)MROWS * (double)DDIM));
}

extern "C" void kernel_launch(void* const* d_in, const int* in_sizes, int n_in,
                              void* d_out, int out_size, void* d_ws, size_t ws_size,
                              hipStream_t stream) {
    const float* x  = (const float*)d_in[0];   // (16,12,4096) f32
    const float* cb = (const float*)d_in[1];   // (1024,492) f32
    float* out = (float*)d_out;

    // workspace layout (~326 KiB)
    char* ws = (char*)d_ws;
    unsigned int* bfp4   = (unsigned int*)ws;                       // 256 KiB
    unsigned int* bscale = (unsigned int*)(ws + (256u << 10));      // 64 KiB
    float* cnorm    = (float*)(ws + (320u << 10));                  // 4 KiB
    float* xsq_part = (float*)(ws + (320u << 10) + 4096);           // 1 KiB
    float* bpart    = (float*)(ws + (320u << 10) + 8192);           // 1 KiB

    prep_bfp4_k<<<64, 256, 0, stream>>>(cb, bfp4, bscale);
    prep_cnorm_k<<<KCODES, 64, 0, stream>>>(cb, cnorm);
    xsq_k<<<256, 256, 0, stream>>>(x, xsq_part);
    vq_main_k<<<NBLK, 1024, 0, stream>>>(x, (const unsigned char*)bfp4,
                                         (const unsigned char*)bscale, cnorm, bpart);
    finalize_k<<<1, 256, 0, stream>>>(bpart, xsq_part, out);
}

// Round 32
// 61.690 us; speedup vs baseline: 1.0096x; 1.0096x over previous
//
#include <hip/hip_runtime.h>

// Problem constants
#define BDIM   16
#define PDIM   12
#define TDIM   4096
#define WINW   41
#define PADW   20
#define DDIM   492      // P*WIN
#define KCODES 1024

// FINAL (R26/R28 config, best measured: 61.0us graph, 59us steady, absmax 0).
// MX-scaled fp8 MFMA (mfma_scale_f32_16x16x128_f8f6f4, scales=1.0), 1024-thr
// blocks (4 waves/SIMD), barrier-free LDS-resident-quarter sweeps.
// Session ladder: 236 (naive MFMA) -> 169 (LDS staging) -> 116 (fp8 32x32)
// -> 93 (8-wave blocks) -> 83 (no-spill) -> 72 (barrier-free quarters)
// -> 61 (MX K=128, 4x fewer MFMA instructions).
// Exhausted levers (documented): reuse-doubling spills at every shape's
// VGPR cap (R21/R27/R29); pipelining/unroll/mov trims all compiler-done
// (R22/R25/R28/R31); fp4-B halves LDS reads but nets ~0 (R30).
#define KCHUNK   4                   // K=128 chunks covering 512
#define TILE_BYTES (KCHUNK * 2 * 64 * 16)   // 8 KiB per 16-code tile

#define WAVES    16                  // 1024-thread blocks (4 waves/SIMD)
#define ROWS_WAVE 16
#define BMROWS   (WAVES * ROWS_WAVE) // 256 rows per block
#define MROWS    (BDIM * TDIM)       // 65536
#define NBLK     (MROWS / BMROWS)    // 256 = 1 block/CU, single round
#define NQ       4                   // codebook quarters
#define QTILES   16                  // 16-code tiles per quarter
#define QBYTES   (QTILES * TILE_BYTES)   // 128 KiB

#define SCALE1   0x7F7F7F7F          // 4x e8m0(127) = 1.0 per 32-elem block

typedef __attribute__((ext_vector_type(4))) float f32x4;
typedef __attribute__((ext_vector_type(2))) long  long2v;
typedef __attribute__((ext_vector_type(4))) int   int4v;
typedef __attribute__((ext_vector_type(8))) int   int8v;

// two f32 pairs -> 4 e4m3 bytes (RNE, saturating) via v_cvt_pk_fp8_f32
__device__ __forceinline__ unsigned int pack4_fp8(float a, float b, float c, float d) {
    int v = 0;
    v = __builtin_amdgcn_cvt_pk_fp8_f32(a, b, v, false);  // bytes 0,1
    v = __builtin_amdgcn_cvt_pk_fp8_f32(c, d, v, true);   // bytes 2,3
    return (unsigned int)v;
}

__device__ __forceinline__ long pack8_fp8(const float* v) {
    unsigned int lo = pack4_fp8(v[0], v[1], v[2], v[3]);
    unsigned int hi = pack4_fp8(v[4], v[5], v[6], v[7]);
    return (long)(((unsigned long long)hi << 32) | lo);
}

// Pre-format codebook into fp8 B-fragments for mfma_scale_f32_16x16x128.
// Entry e = ((nt*KCHUNK + kc)*2 + half)*64 + lane holds 16 bytes:
//   B[k][n], n = nt*16 + (lane&15), k = kc*128 + (lane>>4)*32 + half*16 + jj
//   (jj = 0..15). Within a tile: offset = kc*2048 + half*1024 + lane*16 ->
//   both b128 reads per MFMA are 16B-stride (bank-conflict-free).
__global__ __launch_bounds__(256) void prep_bfrag_k(const float* __restrict__ cb,
                                                    long2v* __restrict__ bfrag) {
    int e    = blockIdx.x * 256 + threadIdx.x;   // 0..32767
    int lane = e & 63;
    int half = (e >> 6) & 1;
    int kc   = (e >> 7) & (KCHUNK - 1);
    int nt   = e >> 9;
    int n    = nt * 16 + (lane & 15);
    int k0   = kc * 128 + (lane >> 4) * 32 + half * 16;
    float v0[8], v1[8];
#pragma unroll
    for (int j = 0; j < 8; ++j) {
        int ka = k0 + j;
        int kb = k0 + 8 + j;
        v0[j] = (ka < DDIM) ? cb[n * DDIM + ka] : 0.f;
        v1[j] = (kb < DDIM) ? cb[n * DDIM + kb] : 0.f;
    }
    long2v out;
    out[0] = pack8_fp8(v0);
    out[1] = pack8_fp8(v1);
    bfrag[e] = out;
}

// Exact fp32 code norms.
__global__ __launch_bounds__(64) void prep_cnorm_k(const float* __restrict__ cb,
                                                   float* __restrict__ cnorm) {
    int n = blockIdx.x;
    int lane = threadIdx.x;
    float s = 0.f;
    for (int d = lane; d < DDIM; d += 64) { float c = cb[n * DDIM + d]; s += c * c; }
#pragma unroll
    for (int m = 1; m < 64; m <<= 1) s += __shfl_xor(s, m, 64);
    if (lane == 0) cnorm[n] = s;
}

// Exact sum of ||f||^2 over all rows via window multiplicity:
// mult(tt) = 41 - max(0,20-tt) - max(0,tt-4075).
__global__ __launch_bounds__(256) void xsq_k(const float* __restrict__ x,
                                             float* __restrict__ xsq_part) {
    float s = 0.f;
    for (int i = blockIdx.x * 256 + threadIdx.x; i < BDIM * PDIM * TDIM; i += 256 * 256) {
        int tt = i & (TDIM - 1);
        int mult = WINW - max(0, PADW - tt) - max(0, tt - (TDIM - 1 - PADW));
        float v = x[i];
        s += (float)mult * v * v;
    }
#pragma unroll
    for (int m = 1; m < 64; m <<= 1) s += __shfl_xor(s, m, 64);
    __shared__ float sm[4];
    if ((threadIdx.x & 63) == 0) sm[threadIdx.x >> 6] = s;
    __syncthreads();
    if (threadIdx.x == 0) xsq_part[blockIdx.x] = sm[0] + sm[1] + sm[2] + sm[3];
}

// Stage one 128 KiB quarter into LDS: 1024 thr x 16 B = 16 KiB per round,
// 8 rounds -> 8 global_load_lds per thread.
__device__ __forceinline__ void stage_quarter(const unsigned char* __restrict__ gq,
                                              unsigned char* smem, int wave, int lane) {
#pragma unroll
    for (int i = 0; i < 8; ++i) {
        int off = i * 16384 + wave * 1024;
        __builtin_amdgcn_global_load_lds(
            (const __attribute__((address_space(1))) unsigned int*)(gq + off + lane * 16),
            (__attribute__((address_space(3))) unsigned int*)(smem + off),
            16, 0, 0);
    }
}

// windowed-x fetch: element d of row with time-index t
__device__ __forceinline__ float fetchx(const float* __restrict__ xb, int t, int d) {
    if (d >= DDIM) return 0.f;
    int p  = d / WINW;
    int w  = d - p * WINW;
    int tt = t + w - PADW;
    return (tt >= 0 && tt < TDIM) ? xb[p * TDIM + tt] : 0.f;
}

// Main sweep: 256 blocks (1/CU) x 16 waves x 16 rows, single round.
// Prologue: stage quarter 0 + sb table + A-build + one sync. Then 4x
// { barrier-free sweep (16 tiles x 4 MX-MFMAs x 8 b128 reads, zero sync
// inside); sync; restage; sync }.
__global__ __launch_bounds__(1024)
void vq_main_k(const float* __restrict__ x,
               const unsigned char* __restrict__ bfrag,
               const float* __restrict__ cnorm,
               float* __restrict__ bpart) {
    __shared__ __align__(16) unsigned char smem[QBYTES];   // 128 KiB
    __shared__ float sb_lds[KCODES];                       // 4 KiB
    __shared__ float gsum[4 * WAVES];

    const int lane = threadIdx.x & 63;
    const int wave = threadIdx.x >> 6;
    const int col  = lane & 15;     // B/D column within 16-code tile
    const int hi   = lane >> 4;
    const int rowbase = blockIdx.x * BMROWS + wave * ROWS_WAVE;

    // Stage quarter 0; latency covered by sb-table + A-build below.
    stage_quarter(bfrag, smem, wave, lane);

    // Full bias table: sb_lds[n] = -0.5*||c_n||^2
    for (int i = threadIdx.x; i < KCODES; i += 1024)
        sb_lds[i] = -0.5f * cnorm[i];

    // ---- fp8 A-build: row = rowbase + col, k = kc*128 + hi*32 + 4m + b ----
    int8v afr[KCHUNK];
    {
        int row = rowbase + col;
        int t = row & (TDIM - 1);
        const float* xb = x + (size_t)(row >> 12) * (PDIM * TDIM);
#pragma unroll
        for (int kc = 0; kc < KCHUNK; ++kc) {
#pragma unroll
            for (int m = 0; m < 8; ++m) {
                int d = kc * 128 + hi * 32 + m * 4;
                float f0 = fetchx(xb, t, d + 0);
                float f1 = fetchx(xb, t, d + 1);
                float f2 = fetchx(xb, t, d + 2);
                float f3 = fetchx(xb, t, d + 3);
                afr[kc][m] = (int)pack4_fp8(f0, f1, f2, f3);
            }
            __builtin_amdgcn_sched_barrier(0);   // bound prologue pressure
        }
    }

    float bs[4];
#pragma unroll
    for (int r = 0; r < 4; ++r) bs[r] = -3.0e38f;

    // Entry drain: quarter 0 resident; sb_lds visible.
    __syncthreads();

    for (int q = 0; q < NQ; ++q) {
        // ---- Barrier-free sweep of the resident quarter ----
        for (int tl = 0; tl < QTILES; ++tl) {
            const unsigned char* tb = smem + tl * TILE_BYTES;
            f32x4 acc = {0.f, 0.f, 0.f, 0.f};
#pragma unroll
            for (int kc = 0; kc < KCHUNK; ++kc) {
                int8v b;
                *(int4v*)&b         = *(const int4v*)(tb + kc * 2048 + lane * 16);
                *(((int4v*)&b) + 1) = *(const int4v*)(tb + kc * 2048 + 1024 + lane * 16);
                acc = __builtin_amdgcn_mfma_scale_f32_16x16x128_f8f6f4(
                          afr[kc], b, acc, 0, 0, 0, SCALE1, 0, SCALE1);
            }
            const float sb = sb_lds[q * (KCODES / NQ) + tl * 16 + col];
#pragma unroll
            for (int r = 0; r < 4; ++r)          // D: col=lane&15, row=hi*4+r
                bs[r] = fmaxf(bs[r], acc[r] + sb);
        }
        // ---- Restage next quarter (2 barriers per transition) ----
        if (q + 1 < NQ) {
            __syncthreads();   // all waves done reading smem
            stage_quarter(bfrag + (size_t)(q + 1) * QBYTES, smem, wave, lane);
            __syncthreads();   // drains vmcnt(0): next quarter resident
        }
    }

    // ---- Per-row max across the 16 col-lanes (masks<16 preserve hi) ----
#pragma unroll
    for (int m = 1; m < 16; m <<= 1)
#pragma unroll
        for (int r = 0; r < 4; ++r)
            bs[r] = fmaxf(bs[r], __shfl_xor(bs[r], m, 64));

    // Lane col==0 of each 16-lane group owns rows {hi*4 + r} of the slab.
    if (col == 0) {
        float s = 0.f;
#pragma unroll
        for (int r = 0; r < 4; ++r) s += bs[r];
        gsum[wave * 4 + hi] = s;
    }
    __syncthreads();
    if (threadIdx.x == 0) {
        float tot = 0.f;
#pragma unroll
        for (int i = 0; i < 4 * WAVES; ++i) tot += gsum[i];
        bpart[blockIdx.x] = tot;
    }
}

// loss = 0.25 * (Sxx - 2*sum_blocks bpart) / (65536*492)
__global__ __launch_bounds__(256) void finalize_k(const float* __restrict__ bpart,
                                                  const float* __restrict__ xsq_part,
                                                  float* __restrict__ out) {
    __shared__ double sm[256];
    int tid = threadIdx.x;
    sm[tid] = (double)bpart[tid];
    __syncthreads();
    for (int st = 128; st > 0; st >>= 1) {
        if (tid < st) sm[tid] += sm[tid + st];
        __syncthreads();
    }
    double S1 = sm[0];
    __syncthreads();
    sm[tid] = (double)xsq_part[tid];
    __syncthreads();
    for (int st = 128; st > 0; st >>= 1) {
        if (tid < st) sm[tid] += sm[tid + st];
        __syncthreads();
    }
    if (tid == 0)
        out[0] = (float)(0.25 * (sm[0] - 2.0 * S1) / ((double)MROWS * (double)DDIM));
}

extern "C" void kernel_launch(void* const* d_in, const int* in_sizes, int n_in,
                              void* d_out, int out_size, void* d_ws, size_t ws_size,
                              hipStream_t stream) {
    const float* x  = (const float*)d_in[0];   // (16,12,4096) f32
    const float* cb = (const float*)d_in[1];   // (1024,492) f32
    float* out = (float*)d_out;

    // workspace layout (~524 KiB)
    char* ws = (char*)d_ws;
    long2v* bfrag   = (long2v*)ws;                                  // 512 KiB
    float* cnorm    = (float*)(ws + (512u << 10));                  // 4 KiB
    float* xsq_part = (float*)(ws + (512u << 10) + 4096);           // 1 KiB
    float* bpart    = (float*)(ws + (512u << 10) + 8192);           // 1 KiB

    prep_bfrag_k<<<128, 256, 0, stream>>>(cb, bfrag);
    prep_cnorm_k<<<KCODES, 64, 0, stream>>>(cb, cnorm);
    xsq_k<<<256, 256, 0, stream>>>(x, xsq_part);
    vq_main_k<<<NBLK, 1024, 0, stream>>>(x, (const unsigned char*)bfrag, cnorm, bpart);
    finalize_k<<<1, 256, 0, stream>>>(bpart, xsq_part, out);
}